// Round 28
// baseline (177.089 us; speedup 1.0000x reference)
//
#include <hip/hip_runtime.h>
#include <math.h>

#define T_SEQ 2048
#define D_MODEL 1024
#define NH 16
#define HD 64
#define RMS_EPS 1.1920928955078125e-07f
#define LOG2E 1.4426950408889634f
#define LN2   0.6931471805599453f

typedef unsigned short ushort_t;
typedef __attribute__((ext_vector_type(8))) short short8;
typedef __attribute__((ext_vector_type(8))) unsigned short ushort8;
typedef __attribute__((ext_vector_type(4))) float f32x4;

static __device__ __forceinline__ unsigned short f2bf(float f) {
    union { float f; unsigned u; } v; v.f = f;
    unsigned r = v.u + 0x7fff + ((v.u >> 16) & 1);   // RNE
    return (unsigned short)(r >> 16);
}
static __device__ __forceinline__ unsigned cvt_pk_bf16(float lo, float hi) {
    unsigned r;
    asm("v_cvt_pk_bf16_f32 %0, %1, %2" : "=v"(r) : "v"(lo), "v"(hi));
    return r;
}
static __device__ __forceinline__ float fast_exp2(float x) {
    float r;
    asm("v_exp_f32 %0, %1" : "=v"(r) : "v"(x));   // bare HW base-2 exp
    return r;
}
static __device__ __forceinline__ void gl_lds16(const ushort_t* g, ushort_t* l) {
    __builtin_amdgcn_global_load_lds(
        (const __attribute__((address_space(1))) unsigned int*)g,
        (__attribute__((address_space(3))) unsigned int*)l, 16, 0, 0);
}

// ---------------------------------------------------------------------------
// Cast f32 -> bf16 (segs 0-5) + RoPE table fill (seg 6). (r26 best config)
// ---------------------------------------------------------------------------
__global__ __launch_bounds__(256) void cast_to_bf16(
    const float* __restrict__ x, const float* __restrict__ wq,
    const float* __restrict__ wk, const float* __restrict__ wv,
    const float* __restrict__ wo,
    ushort_t* __restrict__ xb, ushort_t* __restrict__ wqb,
    ushort_t* __restrict__ wkb, ushort_t* __restrict__ wvb,
    ushort_t* __restrict__ wob, float2* __restrict__ rtab) {
    const int seg = blockIdx.y;
    if (seg == 6) {
        if (blockIdx.x < 256) {
            const int t = blockIdx.x * 8 + (threadIdx.x >> 5);
            const int i = threadIdx.x & 31;
            const float inv = exp2f(-0.4152410118609203f * (float)i);
            float sn, c;
            sincosf((float)t * inv, &sn, &c);
            rtab[t * 32 + i] = make_float2(c, sn);
        }
        return;
    }
    const float* src; ushort_t* dst; size_t base = 0;
    if (seg == 0)      { src = x;  dst = xb; }
    else if (seg == 1) { src = x;  dst = xb; base = 1u << 20; }
    else if (seg == 2) { src = wq; dst = wqb; }
    else if (seg == 3) { src = wk; dst = wkb; }
    else if (seg == 4) { src = wv; dst = wvb; }
    else               { src = wo; dst = wob; }
    const size_t i = base + ((size_t)blockIdx.x * 256 + threadIdx.x) * 8;
    float4 a = *(const float4*)&src[i];
    float4 b = *(const float4*)&src[i + 4];
    ushort8 o;
    o[0] = f2bf(a.x); o[1] = f2bf(a.y); o[2] = f2bf(a.z); o[3] = f2bf(a.w);
    o[4] = f2bf(b.x); o[5] = f2bf(b.y); o[6] = f2bf(b.z); o[7] = f2bf(b.w);
    *(ushort8*)&dst[i] = o;
}

// ---------------------------------------------------------------------------
// Templated bf16 MFMA GEMM v2 (r21: dbuf K-loop LDS, one barrier/iter).
// MODE 0: f32 store (Wo), 64x64 tile. MODE 1: fused QKV epilogue, 64x128;
// q pre-scaled by 0.125*log2e (base-2 softmax downstream; RoPE is linear).
// ---------------------------------------------------------------------------
template<int BM, int BN, int NWM, int NWN, int MODE>
__global__ __launch_bounds__(256) void gemm_bf16_nt(
    const ushort_t* __restrict__ A,
    const ushort_t* __restrict__ B0, const ushort_t* __restrict__ B1,
    const ushort_t* __restrict__ B2,
    void* __restrict__ C0, void* __restrict__ C1, void* __restrict__ C2,
    const float* __restrict__ vi, const float* __restrict__ lamb,
    const float2* __restrict__ rtab,
    int M, int N, int K) {
    constexpr int NT  = 256;
    constexpr int WM  = BM / NWM;
    constexpr int WN  = BN / NWN;
    constexpr int MF  = WM / 16, NF = WN / 16;
    constexpr int RPC = NT / 8;              // rows per 16B staging call
    constexpr int CA  = BM / RPC;
    constexpr int CB  = BN / RPC;
    constexpr int TILE = (BM + BN) * 64;     // elements per K-step buffer

    __shared__ ushort_t smem[2][TILE];       // dbuf: As | Bs per buffer

    const int z = blockIdx.z;
    const ushort_t* B = (z == 0) ? B0 : (z == 1) ? B1 : B2;
    void* Cv          = (z == 0) ? C0 : (z == 1) ? C1 : C2;

    const int tid = threadIdx.x;
    const int w = tid >> 6;
    const int l = tid & 63;
    const int wr = w / NWN, wc = w % NWN;
    const int l16 = l & 15, g4 = l >> 4;
    const int row0 = blockIdx.y * BM;
    const int col0 = blockIdx.x * BN;

    const int srow = tid >> 3;
    const int scol = (tid & 7) * 8;
    const ushort_t* ga = A + (size_t)(row0 + srow) * K + scol;
    const ushort_t* gb = B + (size_t)(col0 + srow) * K + scol;

    f32x4 acc[MF][NF];
#pragma unroll
    for (int m = 0; m < MF; ++m)
#pragma unroll
        for (int n = 0; n < NF; ++n)
            acc[m][n] = (f32x4){0.0f, 0.0f, 0.0f, 0.0f};

    // prologue: DMA K-step 0 into buffer 0
#pragma unroll
    for (int i = 0; i < CA; ++i)
        gl_lds16(ga + (size_t)i * RPC * K, &smem[0][w * 512 + i * NT * 8]);
#pragma unroll
    for (int i = 0; i < CB; ++i)
        gl_lds16(gb + (size_t)i * RPC * K, &smem[0][BM * 64 + w * 512 + i * NT * 8]);

    const int NK = K / 64;
    for (int ks = 0; ks < NK; ++ks) {
        const int cur = ks & 1;

        __syncthreads();   // drains DMA[cur]; all prev reads of [cur^1] done

        if (ks + 1 < NK) {
            const int nxt = cur ^ 1;
            const int k0 = (ks + 1) * 64;
#pragma unroll
            for (int i = 0; i < CA; ++i)
                gl_lds16(ga + (size_t)i * RPC * K + k0, &smem[nxt][w * 512 + i * NT * 8]);
#pragma unroll
            for (int i = 0; i < CB; ++i)
                gl_lds16(gb + (size_t)i * RPC * K + k0, &smem[nxt][BM * 64 + w * 512 + i * NT * 8]);
        }

        const ushort_t* As = &smem[cur][0];
        const ushort_t* Bs = &smem[cur][BM * 64];
#pragma unroll
        for (int kk = 0; kk < 2; ++kk) {
            short8 af[MF], bfr[NF];
#pragma unroll
            for (int m = 0; m < MF; ++m)
                af[m] = *(const short8*)&As[(wr * WM + m * 16 + l16) * 64 + kk * 32 + g4 * 8];
#pragma unroll
            for (int n = 0; n < NF; ++n)
                bfr[n] = *(const short8*)&Bs[(wc * WN + n * 16 + l16) * 64 + kk * 32 + g4 * 8];
#pragma unroll
            for (int m = 0; m < MF; ++m)
#pragma unroll
                for (int n = 0; n < NF; ++n)
                    acc[m][n] = __builtin_amdgcn_mfma_f32_16x16x32_bf16(af[m], bfr[n], acc[m][n], 0, 0, 0);
        }
    }

    if constexpr (MODE == 0) {
#pragma unroll
        for (int m = 0; m < MF; ++m) {
            const int grow = row0 + wr * WM + m * 16 + g4 * 4;
#pragma unroll
            for (int n = 0; n < NF; ++n) {
                const int gcol = col0 + wc * WN + n * 16 + l16;
#pragma unroll
                for (int r = 0; r < 4; ++r)
                    ((float*)Cv)[(size_t)(grow + r) * N + gcol] = acc[m][n][r];
            }
        }
    } else {
        const int hh = blockIdx.x * (BN / 64) + wc;   // this wave's head
        if (z == 2) {
            // V: blend then transposed store vT[h][d][t] via LDS, per head
            const float lam = lamb[0];
            ushort_t* TB = &smem[0][0];       // [64 d][72] u16 = 9216 B
            for (int pass = 0; pass < NWN; ++pass) {
                __syncthreads();              // smem free / prev pass stored
                if (wc == pass) {
#pragma unroll
                    for (int m = 0; m < MF; ++m)
#pragma unroll
                        for (int r = 0; r < 4; ++r) {
                            const int trow = wr * WM + m * 16 + g4 * 4 + r;  // 0..BM-1
                            const int grow = row0 + trow;
#pragma unroll
                            for (int n = 0; n < NF; ++n) {
                                const int d = n * 16 + l16;
                                const float vv = (1.0f - lam) * acc[m][n][r]
                                               + lam * vi[(size_t)grow * D_MODEL + hh * HD + d];
                                TB[d * 72 + trow] = f2bf(vv);
                            }
                        }
                }
                __syncthreads();
                // store head: 64 d-rows x BM(=64) t, swizzled 16B chunks
                const int hs = blockIdx.x * (BN / 64) + pass;
                const int drow = tid >> 2;        // 0..63
                const int q4 = tid & 3;
#pragma unroll
                for (int cc = 0; cc < 2; ++cc) {
                    const int cg = q4 * 2 + cc;   // chunk 0..7 (8 t each)
                    const int cw = cg ^ (drow & 7);
                    const ushort8 val = *(const ushort8*)&TB[drow * 72 + cg * 8];
                    *(ushort8*)&((ushort_t*)Cv)[(size_t)(hs * 64 + drow) * 2048
                                                + row0 + cw * 8] = val;
                }
            }
        } else {
#pragma unroll
            for (int m = 0; m < MF; ++m)
#pragma unroll
                for (int r = 0; r < 4; ++r) {
                    const int row = row0 + wr * WM + m * 16 + g4 * 4 + r;
                    float s = acc[m][0][r] * acc[m][0][r] + acc[m][1][r] * acc[m][1][r]
                            + acc[m][2][r] * acc[m][2][r] + acc[m][3][r] * acc[m][3][r];
                    s += __shfl_xor(s, 1, 64);
                    s += __shfl_xor(s, 2, 64);
                    s += __shfl_xor(s, 4, 64);
                    s += __shfl_xor(s, 8, 64);
                    float rq = rsqrtf(s * (1.0f / 64.0f) + RMS_EPS);
                    if (z == 0) rq *= 0.125f * LOG2E;  // fold score scale + log2e
                    float a[4];
#pragma unroll
                    for (int n = 0; n < 4; ++n) a[n] = acc[m][n][r] * rq;
                    // RoPE via precomputed table (pair d, d+32 = frag n, n+2)
                    const float2 cs0 = rtab[row * 32 + l16];
                    const float2 cs1 = rtab[row * 32 + 16 + l16];
#pragma unroll
                    for (int n = 0; n < 2; ++n) {
                        const float c  = n ? cs1.x : cs0.x;
                        const float sn = n ? cs1.y : cs0.y;
                        const float a0 = a[n], a2 = a[n + 2];
                        a[n]     = a0 * c + a2 * sn;
                        a[n + 2] = -a0 * sn + a2 * c;
                    }
#pragma unroll
                    for (int n = 0; n < 4; ++n) {
                        const int d = n * 16 + l16;
                        int col;
                        if (z == 1)
                            col = hh * HD + ((((d >> 3) ^ (row & 7)) << 3) | (d & 7));
                        else
                            col = hh * HD + d;
                        ((ushort_t*)Cv)[(size_t)row * D_MODEL + col] = f2bf(a[n]);
                    }
                }
        }
    }
}

// ---------------------------------------------------------------------------
// Flash attention v15: v14 + combine FOLDED IN via atomic split counter.
// Each split block writes partials, __threadfence (device scope, cross-XCD),
// atomicAdd on the per-(qt,h) counter; the second arriver merges inline
// (identical math to the old attn_combine -> deterministic values). Deletes
// one kernel launch; merge overlaps the attention tail.
// ---------------------------------------------------------------------------
__global__ __launch_bounds__(256, 4) void attn_mfma(const ushort_t* __restrict__ qb,
                                                    const ushort_t* __restrict__ kb,
                                                    const ushort_t* __restrict__ vT,
                                                    const float* __restrict__ sink,
                                                    ushort_t* __restrict__ yb,
                                                    float* __restrict__ part_acc,
                                                    float* __restrict__ part_ml,
                                                    unsigned* __restrict__ scnt) {
    const int b = blockIdx.x;
    int h, qt, kt0, kt1, mode;   // mode 0 = full->y, 1/2 = partial half 0/1
    if (b < 512) {
        // splits, qt 31..16: b = ((31-qt)*4 + (h>>3)*2 + half)*8 + (h&7)
        const int x = b & 7;
        const int g = b >> 3;                // [0,64)
        qt = 31 - (g >> 2);
        const int hi   = (g >> 1) & 1;
        const int half = g & 1;
        h = hi * 8 + x;
        const int mid = (qt + 1) >> 1;
        kt0 = half ? mid : 0;
        kt1 = half ? (qt + 1) : mid;
        mode = 1 + half;
    } else {
        // full, qt 15..0: (b-512) = (qt'*2 + (h>>3))*8 + (h&7)
        const int idx = b - 512;
        const int x = idx & 7;
        const int g = idx >> 3;              // [0,32)
        qt = 15 - (g >> 1);
        const int hi = g & 1;
        h = hi * 8 + x;
        kt0 = 0; kt1 = qt + 1; mode = 0;
    }

    __shared__ ushort_t Kl[2][64 * 64];     // K tiles (swizzled rows), dbuf: 16 KB
    __shared__ ushort_t Vl[2][64 * 64];     // V^T tiles (swizzled rows), dbuf: 16 KB
    __shared__ ushort_t Pl[4][16 * 64];     // per-wave P, XOR-swizzled: 8 KB

    const int tid  = threadIdx.x;
    const int w    = tid >> 6;
    const int lane = tid & 63;
    const int l16  = lane & 15;
    const int g4   = lane >> 4;

    const size_t qoff = (size_t)(qt * 64 + w * 16 + l16) * D_MODEL + h * HD;
    const short8 q0 = *(const short8*)&qb[qoff + 8 * g4];
    const short8 q1 = *(const short8*)&qb[qoff + 32 + 8 * g4];

    const int srow8  = w * 16 + (lane >> 3);   // staging row (+ i*8)
    const int scol_l = (lane & 7) * 8;

    // prologue: DMA K tile kt0 (rows=keys) and V^T tile kt0 (rows=d)
#pragma unroll
    for (int i = 0; i < 2; ++i) {
        gl_lds16(kb + ((size_t)(kt0 * 64 + srow8 + i * 8) << 10) + h * HD + scol_l,
                 &Kl[kt0 & 1][w * 1024 + i * 512]);
        gl_lds16(vT + ((size_t)(h * 64 + srow8 + i * 8) << 11) + kt0 * 64 + scol_l,
                 &Vl[kt0 & 1][w * 1024 + i * 512]);
    }

    float m = -INFINITY, lsum = 0.0f;   // m in log2 units
    f32x4 acc[4];
#pragma unroll
    for (int d = 0; d < 4; ++d) acc[d] = (f32x4){0.0f, 0.0f, 0.0f, 0.0f};

    for (int kt = kt0; kt < kt1; ++kt) {
        const int cur = kt & 1;

        __syncthreads();   // drains DMA[cur]; all prev reads of [cur^1] done

        // earliest legal DMA issue for next tile (into the just-freed buffer)
        if (kt + 1 < kt1) {
            const int nxt = cur ^ 1;
#pragma unroll
            for (int i = 0; i < 2; ++i) {
                gl_lds16(kb + ((size_t)((kt + 1) * 64 + srow8 + i * 8) << 10) + h * HD + scol_l,
                         &Kl[nxt][w * 1024 + i * 512]);
                gl_lds16(vT + ((size_t)(h * 64 + srow8 + i * 8) << 11) + (kt + 1) * 64 + scol_l,
                         &Vl[nxt][w * 1024 + i * 512]);
            }
        }

        // ---- K A-frags from LDS (swizzled), S^T = K Q^T (log2-scaled) ----
        f32x4 sf[4];
        __builtin_amdgcn_s_setprio(1);
#pragma unroll
        for (int s = 0; s < 4; ++s) {
            const int row = s * 16 + l16;
            const int swz = l16 & 7;
            const short8 ka0 = *(const short8*)&Kl[cur][row * 64 + ((g4 ^ swz) << 3)];
            const short8 ka1 = *(const short8*)&Kl[cur][row * 64 + (((g4 + 4) ^ swz) << 3)];
            f32x4 t = (f32x4){0.0f, 0.0f, 0.0f, 0.0f};
            t = __builtin_amdgcn_mfma_f32_16x16x32_bf16(ka0, q0, t, 0, 0, 0);
            t = __builtin_amdgcn_mfma_f32_16x16x32_bf16(ka1, q1, t, 0, 0, 0);
            sf[s] = t;
        }
        __builtin_amdgcn_s_setprio(0);

        float mt = -INFINITY;
        if (kt == qt) {
            const int ql = w * 16 + l16;
#pragma unroll
            for (int s = 0; s < 4; ++s)
#pragma unroll
                for (int r = 0; r < 4; ++r) {
                    sf[s][r] = (s * 16 + g4 * 4 + r > ql) ? -INFINITY : sf[s][r];
                    mt = fmaxf(mt, sf[s][r]);
                }
        } else {
#pragma unroll
            for (int s = 0; s < 4; ++s)
#pragma unroll
                for (int r = 0; r < 4; ++r)
                    mt = fmaxf(mt, sf[s][r]);
        }
        mt = fmaxf(mt, __shfl_xor(mt, 16, 64));
        mt = fmaxf(mt, __shfl_xor(mt, 32, 64));

        // exact skip: if no row's max grew, corr == 1 and m unchanged
        const bool grow = !__all(mt <= m);
        float corr = 1.0f;
        if (grow) {
            const float mnew = fmaxf(m, mt);
            corr = fast_exp2(m - mnew);
            m = mnew;
        }

        float ps = 0.0f;
#pragma unroll
        for (int s = 0; s < 4; ++s) {
            const float e0 = fast_exp2(sf[s][0] - m);
            const float e1 = fast_exp2(sf[s][1] - m);
            const float e2 = fast_exp2(sf[s][2] - m);
            const float e3 = fast_exp2(sf[s][3] - m);
            ps += (e0 + e1) + (e2 + e3);
            uint2 pkv;
            pkv.x = cvt_pk_bf16(e0, e1);
            pkv.y = cvt_pk_bf16(e2, e3);
            // swizzled P store: 8B slot (g4&1) of 16B chunk (2s+(g4>>1))^(l16&7)
            const int wch = (2 * s + (g4 >> 1)) ^ (l16 & 7);
            *(uint2*)&Pl[w][l16 * 64 + wch * 8 + (g4 & 1) * 4] = pkv;
        }
        ps += __shfl_xor(ps, 16, 64);
        ps += __shfl_xor(ps, 32, 64);

        if (grow) {
            lsum = lsum * corr + ps;
            float corrq[4];
#pragma unroll
            for (int r = 0; r < 4; ++r) corrq[r] = __shfl(corr, g4 * 4 + r, 64);
#pragma unroll
            for (int d = 0; d < 4; ++d)
#pragma unroll
                for (int r = 0; r < 4; ++r) acc[d][r] *= corrq[r];
        } else {
            lsum += ps;
        }

        // ---- PV: P A-frags from swizzled Pl; V B-frags from Vl[cur] ----
        const int swp = l16 & 7;
        const short8 pa0 = *(const short8*)&Pl[w][l16 * 64 + ((g4 ^ swp) << 3)];
        const short8 pa1 = *(const short8*)&Pl[w][l16 * 64 + (((4 + g4) ^ swp) << 3)];
        __builtin_amdgcn_s_setprio(1);
#pragma unroll
        for (int d = 0; d < 4; ++d) {
            const int row = d * 16 + l16;
            const short8 v0 = *(const short8*)&Vl[cur][row * 64 + ((g4 ^ swp) << 3)];
            const short8 v1 = *(const short8*)&Vl[cur][row * 64 + (((g4 + 4) ^ swp) << 3)];
            acc[d] = __builtin_amdgcn_mfma_f32_16x16x32_bf16(pa0, v0, acc[d], 0, 0, 0);
            acc[d] = __builtin_amdgcn_mfma_f32_16x16x32_bf16(pa1, v1, acc[d], 0, 0, 0);
        }
        __builtin_amdgcn_s_setprio(0);
    }

    if (mode == 0) {
        const float lse = m * LN2 + __logf(lsum);
        const float scale = 1.0f / (1.0f + __expf(-(lse - sink[h])));
        const float fv = scale / lsum;
        float fq[4];
#pragma unroll
        for (int r = 0; r < 4; ++r) fq[r] = __shfl(fv, g4 * 4 + r, 64);
#pragma unroll
        for (int r = 0; r < 4; ++r) {
            const size_t yoff = (size_t)(qt * 64 + w * 16 + g4 * 4 + r) * D_MODEL + h * HD + l16;
#pragma unroll
            for (int d = 0; d < 4; ++d)
                yb[yoff + d * 16] = f2bf(acc[d][r] * fq[r]);
        }
    } else {
        const int si = (qt - 16) * 16 + h;
        const int pi = si * 2 + (mode - 1);
        if (g4 == 0) {
            float* ml = part_ml + (size_t)pi * 128;
            ml[w * 16 + l16]      = m;      // log2 units
            ml[64 + w * 16 + l16] = lsum;
        }
        float* pa = part_acc + (size_t)pi * 4096;
#pragma unroll
        for (int r = 0; r < 4; ++r) {
            const int row = w * 16 + g4 * 4 + r;
#pragma unroll
            for (int d = 0; d < 4; ++d)
                pa[row * 64 + d * 16 + l16] = acc[d][r];
        }

        // ---- last-arriver merge (replaces attn_combine kernel) ----
        __threadfence();                    // release partials (device scope)
        if (tid == 0) {
            const unsigned old = atomicAdd(&scnt[si], 1u);
            *(volatile unsigned*)&Pl[0][0] = (old == 1u) ? 1u : 0u;
        }
        __syncthreads();
        if (*(volatile unsigned*)&Pl[0][0]) {
            __threadfence();                // acquire other half's partials
            const int row = tid >> 2;
            const int c0  = (tid & 3) * 16;
            const float* a0 = part_acc + ((size_t)si * 2) * 4096 + row * 64 + c0;
            const float* a1 = a0 + 4096;
            const float* mlp = part_ml + (size_t)si * 2 * 128;
            const float m0 = mlp[row],       l0 = mlp[64 + row];
            const float m1 = mlp[128 + row], l1 = mlp[192 + row];
            const float M  = fmaxf(m0, m1);
            const float e0 = fast_exp2(m0 - M), e1 = fast_exp2(m1 - M);
            const float lc = l0 * e0 + l1 * e1;
            const float lse = M * LN2 + __logf(lc);
            const float scale = 1.0f / (1.0f + __expf(-(lse - sink[h])));
            const float f = scale / lc;
            ushort8 o[2];
#pragma unroll
            for (int j = 0; j < 16; ++j) {
                const float v = (a0[j] * e0 + a1[j] * e1) * f;
                o[j >> 3][j & 7] = f2bf(v);
            }
            ushort_t* yp = yb + (size_t)(qt * 64 + row) * D_MODEL + h * HD + c0;
            *(ushort8*)yp       = o[0];
            *(ushort8*)(yp + 8) = o[1];
        }
    }
}

// ---------------------------------------------------------------------------
extern "C" void kernel_launch(void* const* d_in, const int* in_sizes, int n_in,
                              void* d_out, int out_size, void* d_ws, size_t ws_size,
                              hipStream_t stream) {
    const float* x    = (const float*)d_in[0];
    const float* vi   = (const float*)d_in[1];
    const float* Wq   = (const float*)d_in[2];
    const float* Wk   = (const float*)d_in[3];
    const float* Wv   = (const float*)d_in[4];
    const float* Wo   = (const float*)d_in[5];
    const float* lamb = (const float*)d_in[6];
    const float* sink = (const float*)d_in[7];
    float* out = (float*)d_out;

    const size_t TD = (size_t)T_SEQ * D_MODEL;    // 2M elts
    const size_t WD = (size_t)D_MODEL * D_MODEL;  // 1M elts
    ushort_t* qbuf = (ushort_t*)d_ws;             // [ 0, 4)MB
    ushort_t* kbuf = qbuf + TD;                   // [ 4, 8)MB
    ushort_t* vbuf = kbuf + TD;                   // [ 8,12)MB  (= vT[h][d][t])
    ushort_t* yb   = vbuf + TD;                   // [12,16)MB
    ushort_t* wob  = yb + TD;                     // [16,18)MB
    ushort_t* xb   = wob + WD;                    // [18,22)MB
    ushort_t* wqb  = xb + TD;                     // [22,24)MB
    ushort_t* wkb  = wqb + WD;                    // [24,26)MB
    ushort_t* wvb  = wkb + WD;                    // [26,28)MB
    float2*   rtab = (float2*)(wvb + WD);         // [28,28.5)MB RoPE table
    unsigned* scnt = (unsigned*)(rtab + 65536);   // 1KB split counters
    // attn partials overlay the staging buffers (dead after the QKV GEMM):
    float* part_acc = (float*)xb;                 // 8 MB  [18,26)MB
    float* part_ml  = (float*)wvb;                // 256 KB in [26,28)MB

    hipMemsetAsync(scnt, 0, 256 * sizeof(unsigned), stream);

    cast_to_bf16<<<dim3(512, 7), 256, 0, stream>>>(x, Wq, Wk, Wv, Wo,
                                                   xb, wqb, wkb, wvb, wob, rtab);

    // fused QKV projection + v-blend + RMSNorm + RoPE + K-swizzle + V-transpose
    gemm_bf16_nt<64, 128, 2, 2, 1><<<dim3(D_MODEL / 128, T_SEQ / 64, 3), 256, 0, stream>>>(
        xb, wqb, wkb, wvb, qbuf, kbuf, vbuf, vi, lamb, rtab, T_SEQ, D_MODEL, D_MODEL);

    attn_mfma<<<dim3(768), 256, 0, stream>>>(qbuf, kbuf, vbuf, sink, yb,
                                             part_acc, part_ml, scnt);

    gemm_bf16_nt<64, 64, 2, 2, 0><<<dim3(D_MODEL / 64, T_SEQ / 64, 1), 256, 0, stream>>>(
        yb, wob, wob, wob, out, out, out, nullptr, nullptr, nullptr,
        T_SEQ, D_MODEL, D_MODEL);
}

// Round 29
// 76.563 us; speedup vs baseline: 2.3130x; 2.3130x over previous
//
#include <hip/hip_runtime.h>
#include <math.h>

#define T_SEQ 2048
#define D_MODEL 1024
#define NH 16
#define HD 64
#define RMS_EPS 1.1920928955078125e-07f
#define LOG2E 1.4426950408889634f
#define LN2   0.6931471805599453f

typedef unsigned short ushort_t;
typedef __attribute__((ext_vector_type(8))) short short8;
typedef __attribute__((ext_vector_type(8))) unsigned short ushort8;
typedef __attribute__((ext_vector_type(4))) float f32x4;

static __device__ __forceinline__ unsigned short f2bf(float f) {
    union { float f; unsigned u; } v; v.f = f;
    unsigned r = v.u + 0x7fff + ((v.u >> 16) & 1);   // RNE
    return (unsigned short)(r >> 16);
}
static __device__ __forceinline__ unsigned cvt_pk_bf16(float lo, float hi) {
    unsigned r;
    asm("v_cvt_pk_bf16_f32 %0, %1, %2" : "=v"(r) : "v"(lo), "v"(hi));
    return r;
}
static __device__ __forceinline__ float fast_exp2(float x) {
    float r;
    asm("v_exp_f32 %0, %1" : "=v"(r) : "v"(x));   // bare HW base-2 exp
    return r;
}
static __device__ __forceinline__ void gl_lds16(const ushort_t* g, ushort_t* l) {
    __builtin_amdgcn_global_load_lds(
        (const __attribute__((address_space(1))) unsigned int*)g,
        (__attribute__((address_space(3))) unsigned int*)l, 16, 0, 0);
}

// ---------------------------------------------------------------------------
// Cast f32 -> bf16 (segs 0-5) + RoPE table fill (seg 6).
// ---------------------------------------------------------------------------
__global__ __launch_bounds__(256) void cast_to_bf16(
    const float* __restrict__ x, const float* __restrict__ wq,
    const float* __restrict__ wk, const float* __restrict__ wv,
    const float* __restrict__ wo,
    ushort_t* __restrict__ xb, ushort_t* __restrict__ wqb,
    ushort_t* __restrict__ wkb, ushort_t* __restrict__ wvb,
    ushort_t* __restrict__ wob, float2* __restrict__ rtab) {
    const int seg = blockIdx.y;
    if (seg == 6) {
        if (blockIdx.x < 256) {
            const int t = blockIdx.x * 8 + (threadIdx.x >> 5);
            const int i = threadIdx.x & 31;
            const float inv = exp2f(-0.4152410118609203f * (float)i);
            float sn, c;
            sincosf((float)t * inv, &sn, &c);
            rtab[t * 32 + i] = make_float2(c, sn);
        }
        return;
    }
    const float* src; ushort_t* dst; size_t base = 0;
    if (seg == 0)      { src = x;  dst = xb; }
    else if (seg == 1) { src = x;  dst = xb; base = 1u << 20; }
    else if (seg == 2) { src = wq; dst = wqb; }
    else if (seg == 3) { src = wk; dst = wkb; }
    else if (seg == 4) { src = wv; dst = wvb; }
    else               { src = wo; dst = wob; }
    const size_t i = base + ((size_t)blockIdx.x * 256 + threadIdx.x) * 8;
    float4 a = *(const float4*)&src[i];
    float4 b = *(const float4*)&src[i + 4];
    ushort8 o;
    o[0] = f2bf(a.x); o[1] = f2bf(a.y); o[2] = f2bf(a.z); o[3] = f2bf(a.w);
    o[4] = f2bf(b.x); o[5] = f2bf(b.y); o[6] = f2bf(b.z); o[7] = f2bf(b.w);
    *(ushort8*)&dst[i] = o;
}

// ---------------------------------------------------------------------------
// Templated bf16 MFMA GEMM v2 (r21: dbuf K-loop LDS, one barrier/iter).
// MODE 0: f32 store (Wo), 64x64 tile. MODE 1: fused QKV epilogue, 64x128;
// q pre-scaled by 0.125*log2e (base-2 softmax downstream; RoPE is linear).
// ---------------------------------------------------------------------------
template<int BM, int BN, int NWM, int NWN, int MODE>
__global__ __launch_bounds__(256) void gemm_bf16_nt(
    const ushort_t* __restrict__ A,
    const ushort_t* __restrict__ B0, const ushort_t* __restrict__ B1,
    const ushort_t* __restrict__ B2,
    void* __restrict__ C0, void* __restrict__ C1, void* __restrict__ C2,
    const float* __restrict__ vi, const float* __restrict__ lamb,
    const float2* __restrict__ rtab,
    int M, int N, int K) {
    constexpr int NT  = 256;
    constexpr int WM  = BM / NWM;
    constexpr int WN  = BN / NWN;
    constexpr int MF  = WM / 16, NF = WN / 16;
    constexpr int RPC = NT / 8;              // rows per 16B staging call
    constexpr int CA  = BM / RPC;
    constexpr int CB  = BN / RPC;
    constexpr int TILE = (BM + BN) * 64;     // elements per K-step buffer

    __shared__ ushort_t smem[2][TILE];       // dbuf: As | Bs per buffer

    const int z = blockIdx.z;
    const ushort_t* B = (z == 0) ? B0 : (z == 1) ? B1 : B2;
    void* Cv          = (z == 0) ? C0 : (z == 1) ? C1 : C2;

    const int tid = threadIdx.x;
    const int w = tid >> 6;
    const int l = tid & 63;
    const int wr = w / NWN, wc = w % NWN;
    const int l16 = l & 15, g4 = l >> 4;
    const int row0 = blockIdx.y * BM;
    const int col0 = blockIdx.x * BN;

    const int srow = tid >> 3;
    const int scol = (tid & 7) * 8;
    const ushort_t* ga = A + (size_t)(row0 + srow) * K + scol;
    const ushort_t* gb = B + (size_t)(col0 + srow) * K + scol;

    f32x4 acc[MF][NF];
#pragma unroll
    for (int m = 0; m < MF; ++m)
#pragma unroll
        for (int n = 0; n < NF; ++n)
            acc[m][n] = (f32x4){0.0f, 0.0f, 0.0f, 0.0f};

    // prologue: DMA K-step 0 into buffer 0
#pragma unroll
    for (int i = 0; i < CA; ++i)
        gl_lds16(ga + (size_t)i * RPC * K, &smem[0][w * 512 + i * NT * 8]);
#pragma unroll
    for (int i = 0; i < CB; ++i)
        gl_lds16(gb + (size_t)i * RPC * K, &smem[0][BM * 64 + w * 512 + i * NT * 8]);

    const int NK = K / 64;
    for (int ks = 0; ks < NK; ++ks) {
        const int cur = ks & 1;

        __syncthreads();   // drains DMA[cur]; all prev reads of [cur^1] done

        if (ks + 1 < NK) {
            const int nxt = cur ^ 1;
            const int k0 = (ks + 1) * 64;
#pragma unroll
            for (int i = 0; i < CA; ++i)
                gl_lds16(ga + (size_t)i * RPC * K + k0, &smem[nxt][w * 512 + i * NT * 8]);
#pragma unroll
            for (int i = 0; i < CB; ++i)
                gl_lds16(gb + (size_t)i * RPC * K + k0, &smem[nxt][BM * 64 + w * 512 + i * NT * 8]);
        }

        const ushort_t* As = &smem[cur][0];
        const ushort_t* Bs = &smem[cur][BM * 64];
#pragma unroll
        for (int kk = 0; kk < 2; ++kk) {
            short8 af[MF], bfr[NF];
#pragma unroll
            for (int m = 0; m < MF; ++m)
                af[m] = *(const short8*)&As[(wr * WM + m * 16 + l16) * 64 + kk * 32 + g4 * 8];
#pragma unroll
            for (int n = 0; n < NF; ++n)
                bfr[n] = *(const short8*)&Bs[(wc * WN + n * 16 + l16) * 64 + kk * 32 + g4 * 8];
#pragma unroll
            for (int m = 0; m < MF; ++m)
#pragma unroll
                for (int n = 0; n < NF; ++n)
                    acc[m][n] = __builtin_amdgcn_mfma_f32_16x16x32_bf16(af[m], bfr[n], acc[m][n], 0, 0, 0);
        }
    }

    if constexpr (MODE == 0) {
#pragma unroll
        for (int m = 0; m < MF; ++m) {
            const int grow = row0 + wr * WM + m * 16 + g4 * 4;
#pragma unroll
            for (int n = 0; n < NF; ++n) {
                const int gcol = col0 + wc * WN + n * 16 + l16;
#pragma unroll
                for (int r = 0; r < 4; ++r)
                    ((float*)Cv)[(size_t)(grow + r) * N + gcol] = acc[m][n][r];
            }
        }
    } else {
        const int hh = blockIdx.x * (BN / 64) + wc;   // this wave's head
        if (z == 2) {
            // V: blend then transposed store vT[h][d][t] via LDS, per head
            const float lam = lamb[0];
            ushort_t* TB = &smem[0][0];       // [64 d][72] u16 = 9216 B
            for (int pass = 0; pass < NWN; ++pass) {
                __syncthreads();              // smem free / prev pass stored
                if (wc == pass) {
#pragma unroll
                    for (int m = 0; m < MF; ++m)
#pragma unroll
                        for (int r = 0; r < 4; ++r) {
                            const int trow = wr * WM + m * 16 + g4 * 4 + r;  // 0..BM-1
                            const int grow = row0 + trow;
#pragma unroll
                            for (int n = 0; n < NF; ++n) {
                                const int d = n * 16 + l16;
                                const float vv = (1.0f - lam) * acc[m][n][r]
                                               + lam * vi[(size_t)grow * D_MODEL + hh * HD + d];
                                TB[d * 72 + trow] = f2bf(vv);
                            }
                        }
                }
                __syncthreads();
                // store head: 64 d-rows x BM(=64) t, swizzled 16B chunks
                const int hs = blockIdx.x * (BN / 64) + pass;
                const int drow = tid >> 2;        // 0..63
                const int q4 = tid & 3;
#pragma unroll
                for (int cc = 0; cc < 2; ++cc) {
                    const int cg = q4 * 2 + cc;   // chunk 0..7 (8 t each)
                    const int cw = cg ^ (drow & 7);
                    const ushort8 val = *(const ushort8*)&TB[drow * 72 + cg * 8];
                    *(ushort8*)&((ushort_t*)Cv)[(size_t)(hs * 64 + drow) * 2048
                                                + row0 + cw * 8] = val;
                }
            }
        } else {
#pragma unroll
            for (int m = 0; m < MF; ++m)
#pragma unroll
                for (int r = 0; r < 4; ++r) {
                    const int row = row0 + wr * WM + m * 16 + g4 * 4 + r;
                    float s = acc[m][0][r] * acc[m][0][r] + acc[m][1][r] * acc[m][1][r]
                            + acc[m][2][r] * acc[m][2][r] + acc[m][3][r] * acc[m][3][r];
                    s += __shfl_xor(s, 1, 64);
                    s += __shfl_xor(s, 2, 64);
                    s += __shfl_xor(s, 4, 64);
                    s += __shfl_xor(s, 8, 64);
                    float rq = rsqrtf(s * (1.0f / 64.0f) + RMS_EPS);
                    if (z == 0) rq *= 0.125f * LOG2E;  // fold score scale + log2e
                    float a[4];
#pragma unroll
                    for (int n = 0; n < 4; ++n) a[n] = acc[m][n][r] * rq;
                    // RoPE via precomputed table (pair d, d+32 = frag n, n+2)
                    const float2 cs0 = rtab[row * 32 + l16];
                    const float2 cs1 = rtab[row * 32 + 16 + l16];
#pragma unroll
                    for (int n = 0; n < 2; ++n) {
                        const float c  = n ? cs1.x : cs0.x;
                        const float sn = n ? cs1.y : cs0.y;
                        const float a0 = a[n], a2 = a[n + 2];
                        a[n]     = a0 * c + a2 * sn;
                        a[n + 2] = -a0 * sn + a2 * c;
                    }
#pragma unroll
                    for (int n = 0; n < 4; ++n) {
                        const int d = n * 16 + l16;
                        int col;
                        if (z == 1)
                            col = hh * HD + ((((d >> 3) ^ (row & 7)) << 3) | (d & 7));
                        else
                            col = hh * HD + d;
                        ((ushort_t*)Cv)[(size_t)row * D_MODEL + col] = f2bf(a[n]);
                    }
                }
        }
    }
}

// ---------------------------------------------------------------------------
// Flash attention v14 (r26 best measured): XCD head-affinity mapping,
// base-2 softmax with bare v_exp, exact skip-rescale, K/V via
// global_load_lds dbuf LDS, Pl XOR-swizzled, setprio, split-K.
// ---------------------------------------------------------------------------
__global__ __launch_bounds__(256, 4) void attn_mfma(const ushort_t* __restrict__ qb,
                                                    const ushort_t* __restrict__ kb,
                                                    const ushort_t* __restrict__ vT,
                                                    const float* __restrict__ sink,
                                                    ushort_t* __restrict__ yb,
                                                    float* __restrict__ part_acc,
                                                    float* __restrict__ part_ml) {
    const int b = blockIdx.x;
    int h, qt, kt0, kt1, mode;   // mode 0 = full->y, 1/2 = partial half 0/1
    if (b < 512) {
        // splits, qt 31..16: b = ((31-qt)*4 + (h>>3)*2 + half)*8 + (h&7)
        const int x = b & 7;
        const int g = b >> 3;                // [0,64)
        qt = 31 - (g >> 2);
        const int hi   = (g >> 1) & 1;
        const int half = g & 1;
        h = hi * 8 + x;
        const int mid = (qt + 1) >> 1;
        kt0 = half ? mid : 0;
        kt1 = half ? (qt + 1) : mid;
        mode = 1 + half;
    } else {
        // full, qt 15..0: (b-512) = (qt'*2 + (h>>3))*8 + (h&7)
        const int idx = b - 512;
        const int x = idx & 7;
        const int g = idx >> 3;              // [0,32)
        qt = 15 - (g >> 1);
        const int hi = g & 1;
        h = hi * 8 + x;
        kt0 = 0; kt1 = qt + 1; mode = 0;
    }

    __shared__ ushort_t Kl[2][64 * 64];     // K tiles (swizzled rows), dbuf: 16 KB
    __shared__ ushort_t Vl[2][64 * 64];     // V^T tiles (swizzled rows), dbuf: 16 KB
    __shared__ ushort_t Pl[4][16 * 64];     // per-wave P, XOR-swizzled: 8 KB

    const int tid  = threadIdx.x;
    const int w    = tid >> 6;
    const int lane = tid & 63;
    const int l16  = lane & 15;
    const int g4   = lane >> 4;

    const size_t qoff = (size_t)(qt * 64 + w * 16 + l16) * D_MODEL + h * HD;
    const short8 q0 = *(const short8*)&qb[qoff + 8 * g4];
    const short8 q1 = *(const short8*)&qb[qoff + 32 + 8 * g4];

    const int srow8  = w * 16 + (lane >> 3);   // staging row (+ i*8)
    const int scol_l = (lane & 7) * 8;

    // prologue: DMA K tile kt0 (rows=keys) and V^T tile kt0 (rows=d)
#pragma unroll
    for (int i = 0; i < 2; ++i) {
        gl_lds16(kb + ((size_t)(kt0 * 64 + srow8 + i * 8) << 10) + h * HD + scol_l,
                 &Kl[kt0 & 1][w * 1024 + i * 512]);
        gl_lds16(vT + ((size_t)(h * 64 + srow8 + i * 8) << 11) + kt0 * 64 + scol_l,
                 &Vl[kt0 & 1][w * 1024 + i * 512]);
    }

    float m = -INFINITY, lsum = 0.0f;   // m in log2 units
    f32x4 acc[4];
#pragma unroll
    for (int d = 0; d < 4; ++d) acc[d] = (f32x4){0.0f, 0.0f, 0.0f, 0.0f};

    for (int kt = kt0; kt < kt1; ++kt) {
        const int cur = kt & 1;

        __syncthreads();   // drains DMA[cur]; all prev reads of [cur^1] done

        // earliest legal DMA issue for next tile (into the just-freed buffer)
        if (kt + 1 < kt1) {
            const int nxt = cur ^ 1;
#pragma unroll
            for (int i = 0; i < 2; ++i) {
                gl_lds16(kb + ((size_t)((kt + 1) * 64 + srow8 + i * 8) << 10) + h * HD + scol_l,
                         &Kl[nxt][w * 1024 + i * 512]);
                gl_lds16(vT + ((size_t)(h * 64 + srow8 + i * 8) << 11) + (kt + 1) * 64 + scol_l,
                         &Vl[nxt][w * 1024 + i * 512]);
            }
        }

        // ---- K A-frags from LDS (swizzled), S^T = K Q^T (log2-scaled) ----
        f32x4 sf[4];
        __builtin_amdgcn_s_setprio(1);
#pragma unroll
        for (int s = 0; s < 4; ++s) {
            const int row = s * 16 + l16;
            const int swz = l16 & 7;
            const short8 ka0 = *(const short8*)&Kl[cur][row * 64 + ((g4 ^ swz) << 3)];
            const short8 ka1 = *(const short8*)&Kl[cur][row * 64 + (((g4 + 4) ^ swz) << 3)];
            f32x4 t = (f32x4){0.0f, 0.0f, 0.0f, 0.0f};
            t = __builtin_amdgcn_mfma_f32_16x16x32_bf16(ka0, q0, t, 0, 0, 0);
            t = __builtin_amdgcn_mfma_f32_16x16x32_bf16(ka1, q1, t, 0, 0, 0);
            sf[s] = t;
        }
        __builtin_amdgcn_s_setprio(0);

        float mt = -INFINITY;
        if (kt == qt) {
            const int ql = w * 16 + l16;
#pragma unroll
            for (int s = 0; s < 4; ++s)
#pragma unroll
                for (int r = 0; r < 4; ++r) {
                    sf[s][r] = (s * 16 + g4 * 4 + r > ql) ? -INFINITY : sf[s][r];
                    mt = fmaxf(mt, sf[s][r]);
                }
        } else {
#pragma unroll
            for (int s = 0; s < 4; ++s)
#pragma unroll
                for (int r = 0; r < 4; ++r)
                    mt = fmaxf(mt, sf[s][r]);
        }
        mt = fmaxf(mt, __shfl_xor(mt, 16, 64));
        mt = fmaxf(mt, __shfl_xor(mt, 32, 64));

        // exact skip: if no row's max grew, corr == 1 and m unchanged
        const bool grow = !__all(mt <= m);
        float corr = 1.0f;
        if (grow) {
            const float mnew = fmaxf(m, mt);
            corr = fast_exp2(m - mnew);
            m = mnew;
        }

        float ps = 0.0f;
#pragma unroll
        for (int s = 0; s < 4; ++s) {
            const float e0 = fast_exp2(sf[s][0] - m);
            const float e1 = fast_exp2(sf[s][1] - m);
            const float e2 = fast_exp2(sf[s][2] - m);
            const float e3 = fast_exp2(sf[s][3] - m);
            ps += (e0 + e1) + (e2 + e3);
            uint2 pkv;
            pkv.x = cvt_pk_bf16(e0, e1);
            pkv.y = cvt_pk_bf16(e2, e3);
            // swizzled P store: 8B slot (g4&1) of 16B chunk (2s+(g4>>1))^(l16&7)
            const int wch = (2 * s + (g4 >> 1)) ^ (l16 & 7);
            *(uint2*)&Pl[w][l16 * 64 + wch * 8 + (g4 & 1) * 4] = pkv;
        }
        ps += __shfl_xor(ps, 16, 64);
        ps += __shfl_xor(ps, 32, 64);

        if (grow) {
            lsum = lsum * corr + ps;
            float corrq[4];
#pragma unroll
            for (int r = 0; r < 4; ++r) corrq[r] = __shfl(corr, g4 * 4 + r, 64);
#pragma unroll
            for (int d = 0; d < 4; ++d)
#pragma unroll
                for (int r = 0; r < 4; ++r) acc[d][r] *= corrq[r];
        } else {
            lsum += ps;
        }

        // ---- PV: P A-frags from swizzled Pl; V B-frags from Vl[cur] ----
        const int swp = l16 & 7;
        const short8 pa0 = *(const short8*)&Pl[w][l16 * 64 + ((g4 ^ swp) << 3)];
        const short8 pa1 = *(const short8*)&Pl[w][l16 * 64 + (((4 + g4) ^ swp) << 3)];
        __builtin_amdgcn_s_setprio(1);
#pragma unroll
        for (int d = 0; d < 4; ++d) {
            const int row = d * 16 + l16;
            const short8 v0 = *(const short8*)&Vl[cur][row * 64 + ((g4 ^ swp) << 3)];
            const short8 v1 = *(const short8*)&Vl[cur][row * 64 + (((g4 + 4) ^ swp) << 3)];
            acc[d] = __builtin_amdgcn_mfma_f32_16x16x32_bf16(pa0, v0, acc[d], 0, 0, 0);
            acc[d] = __builtin_amdgcn_mfma_f32_16x16x32_bf16(pa1, v1, acc[d], 0, 0, 0);
        }
        __builtin_amdgcn_s_setprio(0);
    }

    if (mode == 0) {
        const float lse = m * LN2 + __logf(lsum);
        const float scale = 1.0f / (1.0f + __expf(-(lse - sink[h])));
        const float fv = scale / lsum;
        float fq[4];
#pragma unroll
        for (int r = 0; r < 4; ++r) fq[r] = __shfl(fv, g4 * 4 + r, 64);
#pragma unroll
        for (int r = 0; r < 4; ++r) {
            const size_t yoff = (size_t)(qt * 64 + w * 16 + g4 * 4 + r) * D_MODEL + h * HD + l16;
#pragma unroll
            for (int d = 0; d < 4; ++d)
                yb[yoff + d * 16] = f2bf(acc[d][r] * fq[r]);
        }
    } else {
        const int pi = ((qt - 16) * 16 + h) * 2 + (mode - 1);
        if (g4 == 0) {
            float* ml = part_ml + (size_t)pi * 128;
            ml[w * 16 + l16]      = m;      // log2 units
            ml[64 + w * 16 + l16] = lsum;
        }
        float* pa = part_acc + (size_t)pi * 4096;
#pragma unroll
        for (int r = 0; r < 4; ++r) {
            const int row = w * 16 + g4 * 4 + r;
#pragma unroll
            for (int d = 0; d < 4; ++d)
                pa[row * 64 + d * 16 + l16] = acc[d][r];
        }
    }
}

// ---------------------------------------------------------------------------
// Merge the two key-half partials (log2-domain m) for qt>=16 + sink scaling.
// ---------------------------------------------------------------------------
__global__ __launch_bounds__(256) void attn_combine(const float* __restrict__ part_acc,
                                                    const float* __restrict__ part_ml,
                                                    const float* __restrict__ sink,
                                                    ushort_t* __restrict__ yb) {
    const int si = blockIdx.x;          // (qt-16)*16 + h
    const int h  = si & 15;
    const int qt = 16 + (si >> 4);
    const int t  = threadIdx.x;
    const int row = t >> 2;
    const int c0  = (t & 3) * 16;

    const float* a0 = part_acc + ((size_t)si * 2) * 4096 + row * 64 + c0;
    const float* a1 = a0 + 4096;
    const float* ml = part_ml + (size_t)si * 2 * 128;
    const float m0 = ml[row],       l0 = ml[64 + row];
    const float m1 = ml[128 + row], l1 = ml[192 + row];
    const float M  = fmaxf(m0, m1);
    const float e0 = fast_exp2(m0 - M), e1 = fast_exp2(m1 - M);
    const float l  = l0 * e0 + l1 * e1;
    const float lse = M * LN2 + __logf(l);
    const float scale = 1.0f / (1.0f + __expf(-(lse - sink[h])));
    const float f = scale / l;

    ushort8 o[2];
#pragma unroll
    for (int j = 0; j < 16; ++j) {
        const float v = (a0[j] * e0 + a1[j] * e1) * f;
        o[j >> 3][j & 7] = f2bf(v);
    }
    ushort_t* yp = yb + (size_t)(qt * 64 + row) * D_MODEL + h * HD + c0;
    *(ushort8*)yp       = o[0];
    *(ushort8*)(yp + 8) = o[1];
}

// ---------------------------------------------------------------------------
extern "C" void kernel_launch(void* const* d_in, const int* in_sizes, int n_in,
                              void* d_out, int out_size, void* d_ws, size_t ws_size,
                              hipStream_t stream) {
    const float* x    = (const float*)d_in[0];
    const float* vi   = (const float*)d_in[1];
    const float* Wq   = (const float*)d_in[2];
    const float* Wk   = (const float*)d_in[3];
    const float* Wv   = (const float*)d_in[4];
    const float* Wo   = (const float*)d_in[5];
    const float* lamb = (const float*)d_in[6];
    const float* sink = (const float*)d_in[7];
    float* out = (float*)d_out;

    const size_t TD = (size_t)T_SEQ * D_MODEL;    // 2M elts
    const size_t WD = (size_t)D_MODEL * D_MODEL;  // 1M elts
    ushort_t* qbuf = (ushort_t*)d_ws;             // [ 0, 4)MB
    ushort_t* kbuf = qbuf + TD;                   // [ 4, 8)MB
    ushort_t* vbuf = kbuf + TD;                   // [ 8,12)MB  (= vT[h][d][t])
    ushort_t* yb   = vbuf + TD;                   // [12,16)MB
    ushort_t* wob  = yb + TD;                     // [16,18)MB
    ushort_t* xb   = wob + WD;                    // [18,22)MB
    ushort_t* wqb  = xb + TD;                     // [22,24)MB
    ushort_t* wkb  = wqb + WD;                    // [24,26)MB
    ushort_t* wvb  = wkb + WD;                    // [26,28)MB
    float2*   rtab = (float2*)(wvb + WD);         // [28,28.5)MB RoPE table
    // attn partials overlay the staging buffers (dead after the QKV GEMM):
    float* part_acc = (float*)xb;                 // 8 MB  [18,26)MB
    float* part_ml  = (float*)wvb;                // 256 KB in [26,28)MB

    cast_to_bf16<<<dim3(512, 7), 256, 0, stream>>>(x, Wq, Wk, Wv, Wo,
                                                   xb, wqb, wkb, wvb, wob, rtab);

    // fused QKV projection + v-blend + RMSNorm + RoPE + K-swizzle + V-transpose
    gemm_bf16_nt<64, 128, 2, 2, 1><<<dim3(D_MODEL / 128, T_SEQ / 64, 3), 256, 0, stream>>>(
        xb, wqb, wkb, wvb, qbuf, kbuf, vbuf, vi, lamb, rtab, T_SEQ, D_MODEL, D_MODEL);

    attn_mfma<<<dim3(768), 256, 0, stream>>>(qbuf, kbuf, vbuf, sink, yb,
                                             part_acc, part_ml);
    attn_combine<<<dim3(256), 256, 0, stream>>>(part_acc, part_ml, sink, yb);

    gemm_bf16_nt<64, 64, 2, 2, 0><<<dim3(D_MODEL / 64, T_SEQ / 64, 1), 256, 0, stream>>>(
        yb, wob, wob, wob, out, out, out, nullptr, nullptr, nullptr,
        T_SEQ, D_MODEL, D_MODEL);
}